// Round 16
// baseline (60.081 us; speedup 1.0000x reference)
//
#include <hip/hip_runtime.h>
#include <hip/hip_bf16.h>

// ---------------------------------------------------------------------------
// Fused causal attention head: B=4, T=4096, E=128, D=64, fp32 in/out.
// prep_w (W -> WT bf16) -> proj (x@W MFMA; q,k row-major bf16, q pre-scaled
// by 0.125*log2(e); V transposed to vt[d][t]) -> attn_partial (uniform
// triangular grid of 128q x 128k blocks, XCD-chunked block swizzle,
// XOR-SWIZZLED 32KB LDS, 4 blocks/CU no-spill bound, swapped-QK^T
// in-register exp2 softmax, P^T->B-frag via bpermute)
// -> attn_combine (register-array merge). Fallback: direct kernel.
// [R16 = R15 (59.9 us) + XCD-chunked swizzle, single-variable]
// ---------------------------------------------------------------------------

typedef __attribute__((ext_vector_type(4))) float  f32x4;
typedef __attribute__((ext_vector_type(4))) unsigned int u32x4;
typedef __attribute__((ext_vector_type(8))) __bf16 bf16x8;
typedef __attribute__((ext_vector_type(8))) unsigned short u16x8;
typedef __attribute__((ext_vector_type(4))) unsigned short u16x4;

#define T_SEQ 4096
#define DH    64
#define EDIM  128
#define KVB   64
#define QSCALE 0.18033688f   // 0.125 * log2(e): softmax in exp2 domain
#define NTRI  528            // 32*33/2 causal blocks per batch

__device__ __forceinline__ unsigned short f2bf(float f) {
    unsigned int x = __builtin_bit_cast(unsigned int, f);
    unsigned int r = x + 0x7fffu + ((x >> 16) & 1u);   // RNE
    return (unsigned short)(r >> 16);
}

__device__ __forceinline__ unsigned int cvt_pk_bf16(float lo, float hi) {
    unsigned int d;
    asm("v_cvt_pk_bf16_f32 %0, %1, %2" : "=v"(d) : "v"(lo), "v"(hi));
    return d;
}

__device__ __forceinline__ f32x4 mfma_bf16(u16x8 a, u16x8 b, f32x4 c) {
    return __builtin_amdgcn_mfma_f32_16x16x32_bf16(
        __builtin_bit_cast(bf16x8, a), __builtin_bit_cast(bf16x8, b), c, 0, 0, 0);
}

// swizzled LDS byte offsets (write and read use the same involution)
__device__ __forceinline__ int kswz(int row, int bcol) {   // K: [128 rows][128B]
    return row * 128 + (bcol ^ ((row & 7) << 4));
}
__device__ __forceinline__ int vswz(int row, int bcol) {   // V: [64 rows][256B]
    return row * 256 + (bcol ^ ((row & 15) << 4));
}

// --------------------------- prep_w -----------------------------------------
__global__ __launch_bounds__(256) void prep_w_kernel(
    const float* __restrict__ wq, const float* __restrict__ wk,
    const float* __restrict__ wv, unsigned short* __restrict__ wt)
{
    int o = blockIdx.x * 256 + threadIdx.x;
    int m   = o >> 13;
    int rem = o & 8191;
    int d = rem >> 7, e = rem & 127;
    const float* W = (m == 0) ? wq : (m == 1) ? wk : wv;
    wt[o] = f2bf(W[e * DH + d]);
}

// --------------------------- proj: q,k row-major; v transposed --------------
__global__ __launch_bounds__(64) void proj_kernel(
    const float* __restrict__ x, const unsigned short* __restrict__ wt,
    unsigned short* __restrict__ qw, unsigned short* __restrict__ kw,
    unsigned short* __restrict__ vt)
{
    const int l   = threadIdx.x;
    const int l15 = l & 15;
    const int lg  = l >> 4;
    const int row0 = blockIdx.x * 16;      // global row (b*4096 + t)
    const int b    = row0 >> 12;
    const int t0   = row0 & 4095;

    u16x8 af[4];
    #pragma unroll
    for (int kt = 0; kt < 4; ++kt) {
        const float* xp = x + (row0 + l15) * EDIM + kt * 32 + lg * 8;
        f32x4 a = *(const f32x4*)xp;
        f32x4 bb = *(const f32x4*)(xp + 4);
        af[kt] = u16x8{ f2bf(a[0]), f2bf(a[1]), f2bf(a[2]), f2bf(a[3]),
                        f2bf(bb[0]), f2bf(bb[1]), f2bf(bb[2]), f2bf(bb[3]) };
    }

    unsigned short* outs[2] = { qw, kw };
    #pragma unroll
    for (int m = 0; m < 2; ++m) {
        #pragma unroll
        for (int nt = 0; nt < 4; ++nt) {
            f32x4 acc = {};
            #pragma unroll
            for (int kt = 0; kt < 4; ++kt) {
                u16x8 bfrag = *(const u16x8*)(wt + (m * 64 + nt * 16 + l15) * EDIM
                                                 + kt * 32 + lg * 8);
                acc = mfma_bf16(af[kt], bfrag, acc);
            }
            const float sc = (m == 0) ? QSCALE : 1.0f;
            #pragma unroll
            for (int r = 0; r < 4; ++r)
                outs[m][(row0 + lg * 4 + r) * DH + nt * 16 + l15] = f2bf(acc[r] * sc);
        }
    }

    // v: store transposed vt[b][d][t]
    #pragma unroll
    for (int nt = 0; nt < 4; ++nt) {
        f32x4 acc = {};
        #pragma unroll
        for (int kt = 0; kt < 4; ++kt) {
            u16x8 bfrag = *(const u16x8*)(wt + (2 * 64 + nt * 16 + l15) * EDIM
                                             + kt * 32 + lg * 8);
            acc = mfma_bf16(af[kt], bfrag, acc);
        }
        u16x4 pv = { f2bf(acc[0]), f2bf(acc[1]), f2bf(acc[2]), f2bf(acc[3]) };
        *(u16x4*)(vt + ((size_t)(b * DH + nt * 16 + l15)) * T_SEQ + t0 + lg * 4) = pv;
    }
}

// --------------------------- phase 1: uniform triangular flash --------------
__global__ __launch_bounds__(256, 4) void attn_partial_kernel(
    const unsigned short* __restrict__ qg, const unsigned short* __restrict__ kg,
    const unsigned short* __restrict__ vt,
    unsigned short* __restrict__ po, float* __restrict__ pm, float* __restrict__ pl)
{
    // XCD-chunked swizzle: grid 2112 = 8 x 264, bijective since 2112 % 8 == 0.
    // Each XCD gets a contiguous triangle run -> Q panels + K/V chunk streams
    // become same-L2 re-hits instead of L3 round-trips.
    const int phys = blockIdx.x;
    const int bid  = (phys & 7) * 264 + (phys >> 3);
    // compact triangular decode: bid -> (b, q128, ch), ch in [0, q128]
    const int b   = bid / NTRI;
    const int i   = bid - b * NTRI;
    int q = (int)((__builtin_sqrtf((float)(8 * i + 1)) - 1.0f) * 0.5f);
    while (q * (q + 1) / 2 > i) --q;
    while ((q + 1) * (q + 2) / 2 <= i) ++q;
    const int q128 = q;
    const int ch   = i - q * (q + 1) / 2;

    __shared__ char K_ldsb[128 * 128];     // 128 keys x 64 d bf16, swizzled
    __shared__ char V_ldsb[64 * 256];      // 64 d x 128 keys bf16, swizzled

    const int tid = threadIdx.x;
    const int w   = tid >> 6;
    const int l   = tid & 63;
    const int l15 = l & 15;
    const int lg  = l >> 4;

    const int base   = b * T_SEQ;
    const int qrow0w = q128 * 128 + w * 32;
    const int kvb    = ch * 128;           // every chunk is 128 keys

    const unsigned short* kgB = kg + (size_t)base * DH;
    const unsigned short* vtB = vt + (size_t)b * DH * T_SEQ;

    // ---- stage K[128][64] and V^T[64][128], coalesced reg->LDS, swizzled ----
    {
        u16x8 kr[4], vr[4];
        #pragma unroll
        for (int j = 0; j < 4; ++j) {
            int gi = tid + j * 256;                // 0..1023
            kr[j] = *(const u16x8*)(kgB + (size_t)(kvb + (gi >> 3)) * DH + (gi & 7) * 8);
            vr[j] = *(const u16x8*)(vtB + (size_t)(gi >> 4) * T_SEQ + kvb + (gi & 15) * 8);
        }
        #pragma unroll
        for (int j = 0; j < 4; ++j) {
            int gi = tid + j * 256;
            *(u16x8*)&K_ldsb[kswz(gi >> 3, (gi & 7) * 16)]  = kr[j];
            *(u16x8*)&V_ldsb[vswz(gi >> 4, (gi & 15) * 16)] = vr[j];
        }
    }

    // Q fragments
    u16x8 qf[2][2];
    #pragma unroll
    for (int rt = 0; rt < 2; ++rt) {
        const unsigned short* qrow = qg + (base + qrow0w + rt * 16 + l15) * DH;
        qf[rt][0] = *(const u16x8*)(qrow + 0 + lg * 8);
        qf[rt][1] = *(const u16x8*)(qrow + 32 + lg * 8);
    }

    f32x4 o_acc[2][4];
    float m_run[2], l_run[2];
    #pragma unroll
    for (int rt = 0; rt < 2; ++rt) {
        #pragma unroll
        for (int dt = 0; dt < 4; ++dt) o_acc[rt][dt] = f32x4{};
        m_run[rt] = -1e30f; l_run[rt] = 0.0f;
    }

    const int src0 = l15 + 32 * (lg & 1);
    const int src1 = src0 + 16;
    const bool hi  = (lg >> 1) != 0;

    __syncthreads();

    // ---- two 64-key tiles from LDS ----
    #pragma unroll
    for (int tt = 0; tt < 2; ++tt) {
        const int kv0 = kvb + tt * 64;
        if (kv0 > qrow0w + 31) continue;           // wave-uniform causal skip

        u16x8 kf[4][2];
        #pragma unroll
        for (int nt = 0; nt < 4; ++nt)
            #pragma unroll
            for (int kt = 0; kt < 2; ++kt) {
                int krow = tt * 64 + nt * 16 + l15;
                kf[nt][kt] = *(const u16x8*)&K_ldsb[kswz(krow, kt * 64 + lg * 16)];
            }

        f32x4 s[2][4];
        __builtin_amdgcn_s_setprio(1);
        #pragma unroll
        for (int rt = 0; rt < 2; ++rt)
            #pragma unroll
            for (int nt = 0; nt < 4; ++nt) {
                f32x4 a = {};
                a = mfma_bf16(kf[nt][0], qf[rt][0], a);
                a = mfma_bf16(kf[nt][1], qf[rt][1], a);
                s[rt][nt] = a;
            }
        __builtin_amdgcn_s_setprio(0);

        if (kv0 + KVB - 1 > qrow0w) {              // diagonal-straddling mask
            #pragma unroll
            for (int rt = 0; rt < 2; ++rt)
                #pragma unroll
                for (int nt = 0; nt < 4; ++nt)
                    #pragma unroll
                    for (int rr = 0; rr < 4; ++rr) {
                        int kj = kv0 + nt * 16 + lg * 4 + rr;
                        int qi = qrow0w + rt * 16 + l15;
                        if (kj > qi) s[rt][nt][rr] = -1e30f;
                    }
        }

        // in-register online softmax (exp2 domain; 2 shfls per reduce)
        float sc2[2];
        bool grow = false;
        unsigned int pk[2][4][2];
        #pragma unroll
        for (int rt = 0; rt < 2; ++rt) {
            float mx = s[rt][0][0];
            #pragma unroll
            for (int nt = 0; nt < 4; ++nt)
                #pragma unroll
                for (int rr = 0; rr < 4; ++rr)
                    mx = fmaxf(mx, s[rt][nt][rr]);
            mx = fmaxf(mx, __shfl_xor(mx, 16));
            mx = fmaxf(mx, __shfl_xor(mx, 32));

            float mold = m_run[rt];
            float mnew = fmaxf(mold, mx);
            grow |= (mx > mold);
            float sc = exp2f(mold - mnew);
            sc2[rt] = sc;
            m_run[rt] = mnew;

            float rs = 0.0f;
            #pragma unroll
            for (int nt = 0; nt < 4; ++nt)
                #pragma unroll
                for (int rr = 0; rr < 4; ++rr) {
                    float p = exp2f(s[rt][nt][rr] - mnew);
                    s[rt][nt][rr] = p;
                    rs += p;
                }
            rs += __shfl_xor(rs, 16);
            rs += __shfl_xor(rs, 32);
            l_run[rt] = l_run[rt] * sc + rs;

            #pragma unroll
            for (int nt = 0; nt < 4; ++nt) {
                pk[rt][nt][0] = cvt_pk_bf16(s[rt][nt][0], s[rt][nt][1]);
                pk[rt][nt][1] = cvt_pk_bf16(s[rt][nt][2], s[rt][nt][3]);
            }
        }
        if (__any(grow)) {
            #pragma unroll
            for (int rt = 0; rt < 2; ++rt)
                #pragma unroll
                for (int dt = 0; dt < 4; ++dt)
                    o_acc[rt][dt] *= sc2[rt];
        }

        // O^T += V^T P^T (P B-frag via bpermute exchange)
        __builtin_amdgcn_s_setprio(1);
        #pragma unroll
        for (int kt = 0; kt < 2; ++kt) {
            u16x8 vf[4];
            #pragma unroll
            for (int dt = 0; dt < 4; ++dt) {
                int vrow = dt * 16 + l15;
                vf[dt] = *(const u16x8*)&V_ldsb[vswz(vrow, tt * 128 + kt * 64 + lg * 16)];
            }
            #pragma unroll
            for (int rt = 0; rt < 2; ++rt) {
                unsigned int pb[4];
                #pragma unroll
                for (int t = 0; t < 4; ++t) {
                    int src = (t < 2) ? src0 : src1;
                    unsigned int pa  = __shfl(pk[rt][2 * kt][t & 1], src);
                    unsigned int pbv = __shfl(pk[rt][2 * kt + 1][t & 1], src);
                    pb[t] = hi ? pbv : pa;
                }
                u32x4 pbq = { pb[0], pb[1], pb[2], pb[3] };
                u16x8 pbf = __builtin_bit_cast(u16x8, pbq);
                #pragma unroll
                for (int dt = 0; dt < 4; ++dt)
                    o_acc[rt][dt] = mfma_bf16(vf[dt], pbf, o_acc[rt][dt]);
            }
        }
        __builtin_amdgcn_s_setprio(0);
    }

    // ---- write partials (bf16 O, f32 m/l); slot = compact triangular idx ----
    const int pidx = bid;
    unsigned short* pob = po + (size_t)pidx * 8192;   // [128][64] bf16
    #pragma unroll
    for (int rt = 0; rt < 2; ++rt) {
        int row = w * 32 + rt * 16 + l15;
        #pragma unroll
        for (int dt = 0; dt < 4; ++dt) {
            unsigned int w0 = cvt_pk_bf16(o_acc[rt][dt][0], o_acc[rt][dt][1]);
            unsigned int w1 = cvt_pk_bf16(o_acc[rt][dt][2], o_acc[rt][dt][3]);
            *(unsigned int*)&pob[row * 64 + dt * 16 + lg * 4]     = w0;
            *(unsigned int*)&pob[row * 64 + dt * 16 + lg * 4 + 2] = w1;
        }
        if (lg == 0) {
            pm[pidx * 128 + row] = m_run[rt];
            pl[pidx * 128 + row] = l_run[rt];
        }
    }
}

// --------------------------- phase 2: combine (register-array merge) --------
__global__ __launch_bounds__(256) void attn_combine_kernel(
    const unsigned short* __restrict__ po, const float* __restrict__ pm,
    const float* __restrict__ pl, float* __restrict__ out)
{
    const int blk   = blockIdx.x;          // (b*32 + q128)*4 + slice
    const int slice = blk & 3;
    const int tb    = blk >> 2;            // b*32 + q128
    const int q128  = tb & 31;
    const int b     = tb >> 5;
    const int nch   = q128 + 1;
    const int bslot = b * NTRI + q128 * (q128 + 1) / 2;
    const int row   = slice * 32 + (threadIdx.x >> 3);   // 0..127
    const int d0    = (threadIdx.x & 7) * 8;

    // load all chunk maxima once into registers (static indexing, all in flight)
    float m_i[32];
    #pragma unroll
    for (int i = 0; i < 32; ++i) {
        int ii = (i < nch) ? i : 0;
        m_i[i] = pm[(bslot + ii) * 128 + row];
    }
    float mstar = m_i[0];
    #pragma unroll
    for (int i = 1; i < 32; ++i)
        if (i < nch) mstar = fmaxf(mstar, m_i[i]);

    float lsum = 0.0f;
    float a[8] = {};
    #pragma unroll
    for (int i = 0; i < 32; ++i) {
        if (i < nch) {
            float wi = exp2f(m_i[i] - mstar);
            lsum += wi * pl[(bslot + i) * 128 + row];
            u16x8 v = *(const u16x8*)&po[(size_t)(bslot + i) * 8192 + row * 64 + d0];
            #pragma unroll
            for (int j = 0; j < 8; ++j) {
                unsigned int u = (unsigned int)v[j] << 16;
                a[j] += wi * __builtin_bit_cast(float, u);
            }
        }
    }
    const float inv = 1.0f / lsum;
    float* op = out + (size_t)(b * T_SEQ + q128 * 128 + row) * DH + d0;
    f32x4 o0 = { a[0] * inv, a[1] * inv, a[2] * inv, a[3] * inv };
    f32x4 o1 = { a[4] * inv, a[5] * inv, a[6] * inv, a[7] * inv };
    *(f32x4*)op = o0;
    *(f32x4*)(op + 4) = o1;
}

// --------------------------- fallback: direct (global K/V reads) ------------
__global__ __launch_bounds__(64, 4) void attn_direct_kernel(
    const unsigned short* __restrict__ qg, const unsigned short* __restrict__ kg,
    const unsigned short* __restrict__ vt, float* __restrict__ out)
{
    const int bid = blockIdx.x;           // b*128 + q32
    const int q32 = bid & 127;
    const int b   = bid >> 7;
    const int l = threadIdx.x, l15 = l & 15, lg = l >> 4;
    const int qrow0 = q32 * 32;
    const int base  = b * T_SEQ;
    const unsigned short* kp = kg + (size_t)base * DH;
    const unsigned short* vp = vt + (size_t)b * DH * T_SEQ;

    u16x8 qf[2][2];
    #pragma unroll
    for (int rt = 0; rt < 2; ++rt) {
        const unsigned short* qrow = qg + (base + qrow0 + rt * 16 + l15) * DH;
        qf[rt][0] = *(const u16x8*)(qrow + 0 + lg * 8);
        qf[rt][1] = *(const u16x8*)(qrow + 32 + lg * 8);
    }

    f32x4 o_acc[2][4];
    float m_run[2], l_run[2];
    #pragma unroll
    for (int rt = 0; rt < 2; ++rt) {
        #pragma unroll
        for (int dt = 0; dt < 4; ++dt) o_acc[rt][dt] = f32x4{};
        m_run[rt] = -1e30f; l_run[rt] = 0.0f;
    }

    const int src0 = l15 + 32 * (lg & 1);
    const int src1 = src0 + 16;
    const bool hi  = (lg >> 1) != 0;

    for (int kv0 = 0; kv0 <= qrow0 + 31; kv0 += KVB) {
        u16x8 kf[4][2];
        #pragma unroll
        for (int nt = 0; nt < 4; ++nt)
            #pragma unroll
            for (int kt = 0; kt < 2; ++kt)
                kf[nt][kt] = *(const u16x8*)(kp + (kv0 + nt * 16 + l15) * DH
                                                + kt * 32 + lg * 8);
        f32x4 s[2][4];
        #pragma unroll
        for (int rt = 0; rt < 2; ++rt)
            #pragma unroll
            for (int nt = 0; nt < 4; ++nt) {
                f32x4 a = {};
                a = mfma_bf16(kf[nt][0], qf[rt][0], a);
                a = mfma_bf16(kf[nt][1], qf[rt][1], a);
                s[rt][nt] = a;
            }
        if (kv0 + KVB - 1 > qrow0) {
            #pragma unroll
            for (int rt = 0; rt < 2; ++rt)
                #pragma unroll
                for (int nt = 0; nt < 4; ++nt)
                    #pragma unroll
                    for (int rr = 0; rr < 4; ++rr) {
                        int kj = kv0 + nt * 16 + lg * 4 + rr;
                        int qi = qrow0 + rt * 16 + l15;
                        if (kj > qi) s[rt][nt][rr] = -1e30f;
                    }
        }
        float sc2[2];
        bool grow = false;
        unsigned int pk[2][4][2];
        #pragma unroll
        for (int rt = 0; rt < 2; ++rt) {
            float mx = s[rt][0][0];
            #pragma unroll
            for (int nt = 0; nt < 4; ++nt)
                #pragma unroll
                for (int rr = 0; rr < 4; ++rr)
                    mx = fmaxf(mx, s[rt][nt][rr]);
            mx = fmaxf(mx, __shfl_xor(mx, 16));
            mx = fmaxf(mx, __shfl_xor(mx, 32));
            float mold = m_run[rt];
            float mnew = fmaxf(mold, mx);
            grow |= (mx > mold);
            float sc = exp2f(mold - mnew);
            sc2[rt] = sc;
            m_run[rt] = mnew;
            float rs = 0.0f;
            #pragma unroll
            for (int nt = 0; nt < 4; ++nt)
                #pragma unroll
                for (int rr = 0; rr < 4; ++rr) {
                    float p = exp2f(s[rt][nt][rr] - mnew);
                    s[rt][nt][rr] = p;
                    rs += p;
                }
            rs += __shfl_xor(rs, 16);
            rs += __shfl_xor(rs, 32);
            l_run[rt] = l_run[rt] * sc + rs;
            #pragma unroll
            for (int nt = 0; nt < 4; ++nt) {
                pk[rt][nt][0] = cvt_pk_bf16(s[rt][nt][0], s[rt][nt][1]);
                pk[rt][nt][1] = cvt_pk_bf16(s[rt][nt][2], s[rt][nt][3]);
            }
        }
        if (__any(grow)) {
            #pragma unroll
            for (int rt = 0; rt < 2; ++rt)
                #pragma unroll
                for (int dt = 0; dt < 4; ++dt)
                    o_acc[rt][dt] *= sc2[rt];
        }
        #pragma unroll
        for (int kt = 0; kt < 2; ++kt) {
            u16x8 vf[4];
            #pragma unroll
            for (int dt = 0; dt < 4; ++dt)
                vf[dt] = *(const u16x8*)(vp + (size_t)(dt * 16 + l15) * T_SEQ
                                            + kv0 + kt * 32 + lg * 8);
            #pragma unroll
            for (int rt = 0; rt < 2; ++rt) {
                unsigned int pb[4];
                #pragma unroll
                for (int t = 0; t < 4; ++t) {
                    int src = (t < 2) ? src0 : src1;
                    unsigned int pa  = __shfl(pk[rt][2 * kt][t & 1], src);
                    unsigned int pbv = __shfl(pk[rt][2 * kt + 1][t & 1], src);
                    pb[t] = hi ? pbv : pa;
                }
                u32x4 pbq = { pb[0], pb[1], pb[2], pb[3] };
                u16x8 pbf = __builtin_bit_cast(u16x8, pbq);
                #pragma unroll
                for (int dt = 0; dt < 4; ++dt)
                    o_acc[rt][dt] = mfma_bf16(vf[dt], pbf, o_acc[rt][dt]);
            }
        }
    }

    #pragma unroll
    for (int rt = 0; rt < 2; ++rt) {
        float inv = 1.0f / l_run[rt];
        int row = base + qrow0 + rt * 16 + l15;
        #pragma unroll
        for (int dt = 0; dt < 4; ++dt) {
            f32x4 ov = o_acc[rt][dt] * inv;
            *(f32x4*)&out[(size_t)row * DH + dt * 16 + lg * 4] = ov;
        }
    }
}

// ---------------------------------------------------------------------------
extern "C" void kernel_launch(void* const* d_in, const int* in_sizes, int n_in,
                              void* d_out, int out_size, void* d_ws, size_t ws_size,
                              hipStream_t stream)
{
    const float* x  = (const float*)d_in[0];
    const float* wq = (const float*)d_in[1];
    const float* wk = (const float*)d_in[2];
    const float* wv = (const float*)d_in[3];
    float* out = (float*)d_out;

    // ws layout:
    //   wt  bf16 [3][64][128]        @ 0        (reserve 64 KB)
    //   qw  bf16 [16384][64]         @ 65536    (2 MB)
    //   kw  bf16 [16384][64]         @ +2 MB
    //   vt  bf16 [4][64][4096]       @ +4 MB
    //   po  bf16 [2112][128][64]     @ 6356992  (34.6 MB, compact triangular)
    //   pm/pl f32 [2112][128]        (1.08 MB each)
    unsigned short* wt = (unsigned short*)d_ws;
    unsigned short* qw = (unsigned short*)((char*)d_ws + 65536);
    unsigned short* kw = qw + (size_t)16384 * DH;
    unsigned short* vt = kw + (size_t)16384 * DH;

    const size_t slots  = 4u * NTRI;                  // 2112
    const size_t po_off = 65536u + 3u * 16384u * DH * 2u;
    const size_t po_sz  = slots * 8192 * 2;
    const size_t pm_off = po_off + po_sz;
    const size_t pl_off = pm_off + slots * 128 * 4;
    const size_t need   = pl_off + slots * 128 * 4;

    prep_w_kernel<<<96, 256, 0, stream>>>(wq, wk, wv, wt);
    proj_kernel<<<1024, 64, 0, stream>>>(x, wt, qw, kw, vt);

    if (ws_size >= need) {
        unsigned short* po = (unsigned short*)((char*)d_ws + po_off);
        float* pm = (float*)((char*)d_ws + pm_off);
        float* pl = (float*)((char*)d_ws + pl_off);
        attn_partial_kernel<<<4 * NTRI, 256, 0, stream>>>(qw, kw, vt, po, pm, pl);
        attn_combine_kernel<<<4 * 32 * 4, 256, 0, stream>>>(po, pm, pl, out);
    } else {
        attn_direct_kernel<<<4 * 128, 64, 0, stream>>>(qw, kw, vt, out);
    }
}

// Round 17
// 58.885 us; speedup vs baseline: 1.0203x; 1.0203x over previous
//
#include <hip/hip_runtime.h>
#include <hip/hip_bf16.h>

// ---------------------------------------------------------------------------
// Fused causal attention head: B=4, T=4096, E=128, D=64, fp32 in/out.
// prep_w (W -> WT bf16) -> proj (x@W MFMA; q,k row-major bf16, q pre-scaled
// by 0.125*log2(e); V transposed to vt[d][t]) -> attn_partial (uniform
// triangular grid of 128q x 128k blocks, XCD-chunked swizzle, XOR-swizzled
// 32KB LDS, swapped-QK^T with PLAIN per-chunk softmax (no online rescale:
// S over all 128 keys first, one reduce/exp/pack per rt, shared-V PV pass))
// -> attn_combine (register-array merge). Fallback: direct kernel.
// [R17 = R16 + merged per-chunk softmax, launch_bounds(256,3)]
// ---------------------------------------------------------------------------

typedef __attribute__((ext_vector_type(4))) float  f32x4;
typedef __attribute__((ext_vector_type(4))) unsigned int u32x4;
typedef __attribute__((ext_vector_type(8))) __bf16 bf16x8;
typedef __attribute__((ext_vector_type(8))) unsigned short u16x8;
typedef __attribute__((ext_vector_type(4))) unsigned short u16x4;

#define T_SEQ 4096
#define DH    64
#define EDIM  128
#define KVB   64
#define QSCALE 0.18033688f   // 0.125 * log2(e): softmax in exp2 domain
#define NTRI  528            // 32*33/2 causal blocks per batch

__device__ __forceinline__ unsigned short f2bf(float f) {
    unsigned int x = __builtin_bit_cast(unsigned int, f);
    unsigned int r = x + 0x7fffu + ((x >> 16) & 1u);   // RNE
    return (unsigned short)(r >> 16);
}

__device__ __forceinline__ unsigned int cvt_pk_bf16(float lo, float hi) {
    unsigned int d;
    asm("v_cvt_pk_bf16_f32 %0, %1, %2" : "=v"(d) : "v"(lo), "v"(hi));
    return d;
}

__device__ __forceinline__ f32x4 mfma_bf16(u16x8 a, u16x8 b, f32x4 c) {
    return __builtin_amdgcn_mfma_f32_16x16x32_bf16(
        __builtin_bit_cast(bf16x8, a), __builtin_bit_cast(bf16x8, b), c, 0, 0, 0);
}

// swizzled LDS byte offsets (write and read use the same involution)
__device__ __forceinline__ int kswz(int row, int bcol) {   // K: [128 rows][128B]
    return row * 128 + (bcol ^ ((row & 7) << 4));
}
__device__ __forceinline__ int vswz(int row, int bcol) {   // V: [64 rows][256B]
    return row * 256 + (bcol ^ ((row & 15) << 4));
}

// --------------------------- prep_w -----------------------------------------
__global__ __launch_bounds__(256) void prep_w_kernel(
    const float* __restrict__ wq, const float* __restrict__ wk,
    const float* __restrict__ wv, unsigned short* __restrict__ wt)
{
    int o = blockIdx.x * 256 + threadIdx.x;
    int m   = o >> 13;
    int rem = o & 8191;
    int d = rem >> 7, e = rem & 127;
    const float* W = (m == 0) ? wq : (m == 1) ? wk : wv;
    wt[o] = f2bf(W[e * DH + d]);
}

// --------------------------- proj: q,k row-major; v transposed --------------
__global__ __launch_bounds__(64) void proj_kernel(
    const float* __restrict__ x, const unsigned short* __restrict__ wt,
    unsigned short* __restrict__ qw, unsigned short* __restrict__ kw,
    unsigned short* __restrict__ vt)
{
    const int l   = threadIdx.x;
    const int l15 = l & 15;
    const int lg  = l >> 4;
    const int row0 = blockIdx.x * 16;      // global row (b*4096 + t)
    const int b    = row0 >> 12;
    const int t0   = row0 & 4095;

    u16x8 af[4];
    #pragma unroll
    for (int kt = 0; kt < 4; ++kt) {
        const float* xp = x + (row0 + l15) * EDIM + kt * 32 + lg * 8;
        f32x4 a = *(const f32x4*)xp;
        f32x4 bb = *(const f32x4*)(xp + 4);
        af[kt] = u16x8{ f2bf(a[0]), f2bf(a[1]), f2bf(a[2]), f2bf(a[3]),
                        f2bf(bb[0]), f2bf(bb[1]), f2bf(bb[2]), f2bf(bb[3]) };
    }

    unsigned short* outs[2] = { qw, kw };
    #pragma unroll
    for (int m = 0; m < 2; ++m) {
        #pragma unroll
        for (int nt = 0; nt < 4; ++nt) {
            f32x4 acc = {};
            #pragma unroll
            for (int kt = 0; kt < 4; ++kt) {
                u16x8 bfrag = *(const u16x8*)(wt + (m * 64 + nt * 16 + l15) * EDIM
                                                 + kt * 32 + lg * 8);
                acc = mfma_bf16(af[kt], bfrag, acc);
            }
            const float sc = (m == 0) ? QSCALE : 1.0f;
            #pragma unroll
            for (int r = 0; r < 4; ++r)
                outs[m][(row0 + lg * 4 + r) * DH + nt * 16 + l15] = f2bf(acc[r] * sc);
        }
    }

    // v: store transposed vt[b][d][t]
    #pragma unroll
    for (int nt = 0; nt < 4; ++nt) {
        f32x4 acc = {};
        #pragma unroll
        for (int kt = 0; kt < 4; ++kt) {
            u16x8 bfrag = *(const u16x8*)(wt + (2 * 64 + nt * 16 + l15) * EDIM
                                             + kt * 32 + lg * 8);
            acc = mfma_bf16(af[kt], bfrag, acc);
        }
        u16x4 pv = { f2bf(acc[0]), f2bf(acc[1]), f2bf(acc[2]), f2bf(acc[3]) };
        *(u16x4*)(vt + ((size_t)(b * DH + nt * 16 + l15)) * T_SEQ + t0 + lg * 4) = pv;
    }
}

// --------------------------- phase 1: uniform triangular flash --------------
__global__ __launch_bounds__(256, 3) void attn_partial_kernel(
    const unsigned short* __restrict__ qg, const unsigned short* __restrict__ kg,
    const unsigned short* __restrict__ vt,
    unsigned short* __restrict__ po, float* __restrict__ pm, float* __restrict__ pl)
{
    // XCD-chunked swizzle: grid 2112 = 8 x 264, bijective since 2112 % 8 == 0.
    const int phys = blockIdx.x;
    const int bid  = (phys & 7) * 264 + (phys >> 3);
    // compact triangular decode: bid -> (b, q128, ch), ch in [0, q128]
    const int b   = bid / NTRI;
    const int i   = bid - b * NTRI;
    int q = (int)((__builtin_sqrtf((float)(8 * i + 1)) - 1.0f) * 0.5f);
    while (q * (q + 1) / 2 > i) --q;
    while ((q + 1) * (q + 2) / 2 <= i) ++q;
    const int q128 = q;
    const int ch   = i - q * (q + 1) / 2;

    __shared__ char K_ldsb[128 * 128];     // 128 keys x 64 d bf16, swizzled
    __shared__ char V_ldsb[64 * 256];      // 64 d x 128 keys bf16, swizzled

    const int tid = threadIdx.x;
    const int w   = tid >> 6;
    const int l   = tid & 63;
    const int l15 = l & 15;
    const int lg  = l >> 4;

    const int base   = b * T_SEQ;
    const int qrow0w = q128 * 128 + w * 32;
    const int kvb    = ch * 128;           // every chunk is 128 keys

    const unsigned short* kgB = kg + (size_t)base * DH;
    const unsigned short* vtB = vt + (size_t)b * DH * T_SEQ;

    // ---- stage K[128][64] and V^T[64][128], coalesced reg->LDS, swizzled ----
    {
        u16x8 kr[4], vr[4];
        #pragma unroll
        for (int j = 0; j < 4; ++j) {
            int gi = tid + j * 256;                // 0..1023
            kr[j] = *(const u16x8*)(kgB + (size_t)(kvb + (gi >> 3)) * DH + (gi & 7) * 8);
            vr[j] = *(const u16x8*)(vtB + (size_t)(gi >> 4) * T_SEQ + kvb + (gi & 15) * 8);
        }
        #pragma unroll
        for (int j = 0; j < 4; ++j) {
            int gi = tid + j * 256;
            *(u16x8*)&K_ldsb[kswz(gi >> 3, (gi & 7) * 16)]  = kr[j];
            *(u16x8*)&V_ldsb[vswz(gi >> 4, (gi & 15) * 16)] = vr[j];
        }
    }

    // Q fragments
    u16x8 qf[2][2];
    #pragma unroll
    for (int rt = 0; rt < 2; ++rt) {
        const unsigned short* qrow = qg + (base + qrow0w + rt * 16 + l15) * DH;
        qf[rt][0] = *(const u16x8*)(qrow + 0 + lg * 8);
        qf[rt][1] = *(const u16x8*)(qrow + 32 + lg * 8);
    }

    f32x4 o_acc[2][4];
    #pragma unroll
    for (int rt = 0; rt < 2; ++rt)
        #pragma unroll
        for (int dt = 0; dt < 4; ++dt) o_acc[rt][dt] = f32x4{};

    const int src0 = l15 + 32 * (lg & 1);
    const int src1 = src0 + 16;
    const bool hi  = (lg >> 1) != 0;

    __syncthreads();

    // tile-1 (keys kvb+64..kvb+127) has any unmasked keys for this wave?
    const bool t1        = (kvb + 64 <= qrow0w + 31);
    const bool need_mask = (kvb + 127 > qrow0w);

    float msv[2], lsv[2];
    unsigned int pk2[2][8][2];

    // ---- per-rt: S over all 128 keys, ONE plain softmax (no online) ----
    #pragma unroll
    for (int rt = 0; rt < 2; ++rt) {
        f32x4 s[8];
        #pragma unroll
        for (int nt = 0; nt < 8; ++nt)
            s[nt] = f32x4{ -1e30f, -1e30f, -1e30f, -1e30f };

        __builtin_amdgcn_s_setprio(1);
        #pragma unroll
        for (int nt = 0; nt < 4; ++nt) {
            int krow = nt * 16 + l15;
            u16x8 k0 = *(const u16x8*)&K_ldsb[kswz(krow, 0 + lg * 16)];
            u16x8 k1 = *(const u16x8*)&K_ldsb[kswz(krow, 64 + lg * 16)];
            f32x4 a = {};
            a = mfma_bf16(k0, qf[rt][0], a);
            a = mfma_bf16(k1, qf[rt][1], a);
            s[nt] = a;
        }
        if (t1) {
            #pragma unroll
            for (int nt = 0; nt < 4; ++nt) {
                int krow = 64 + nt * 16 + l15;
                u16x8 k0 = *(const u16x8*)&K_ldsb[kswz(krow, 0 + lg * 16)];
                u16x8 k1 = *(const u16x8*)&K_ldsb[kswz(krow, 64 + lg * 16)];
                f32x4 a = {};
                a = mfma_bf16(k0, qf[rt][0], a);
                a = mfma_bf16(k1, qf[rt][1], a);
                s[4 + nt] = a;
            }
        }
        __builtin_amdgcn_s_setprio(0);

        if (need_mask) {                       // diagonal chunk only
            const int qi = qrow0w + rt * 16 + l15;
            #pragma unroll
            for (int nt = 0; nt < 8; ++nt)
                #pragma unroll
                for (int rr = 0; rr < 4; ++rr) {
                    int kj = kvb + nt * 16 + lg * 4 + rr;
                    if (kj > qi) s[nt][rr] = -1e30f;
                }
        }

        // plain softmax over the chunk (2 shfls total)
        float mx = s[0][0];
        #pragma unroll
        for (int nt = 0; nt < 8; ++nt)
            #pragma unroll
            for (int rr = 0; rr < 4; ++rr)
                mx = fmaxf(mx, s[nt][rr]);
        mx = fmaxf(mx, __shfl_xor(mx, 16));
        mx = fmaxf(mx, __shfl_xor(mx, 32));

        float rs = 0.0f;
        #pragma unroll
        for (int nt = 0; nt < 8; ++nt) {
            float e0 = exp2f(s[nt][0] - mx);
            float e1 = exp2f(s[nt][1] - mx);
            float e2 = exp2f(s[nt][2] - mx);
            float e3 = exp2f(s[nt][3] - mx);
            rs += (e0 + e1) + (e2 + e3);
            pk2[rt][nt][0] = cvt_pk_bf16(e0, e1);
            pk2[rt][nt][1] = cvt_pk_bf16(e2, e3);
        }
        rs += __shfl_xor(rs, 16);
        rs += __shfl_xor(rs, 32);
        msv[rt] = mx;
        lsv[rt] = rs;
    }

    // ---- PV: 4 k-slices of 32 keys; V-frags shared by both rt ----
    __builtin_amdgcn_s_setprio(1);
    #pragma unroll
    for (int kt = 0; kt < 4; ++kt) {
        if (kt >= 2 && !t1) continue;          // tile-1 fully masked: pk are 0
        u16x8 vf[4];
        #pragma unroll
        for (int dt = 0; dt < 4; ++dt) {
            int vrow = dt * 16 + l15;
            vf[dt] = *(const u16x8*)&V_ldsb[vswz(vrow, kt * 64 + lg * 16)];
        }
        #pragma unroll
        for (int rt = 0; rt < 2; ++rt) {
            unsigned int pb[4];
            #pragma unroll
            for (int t = 0; t < 4; ++t) {
                int src = (t < 2) ? src0 : src1;
                unsigned int pa  = __shfl(pk2[rt][2 * kt][t & 1], src);
                unsigned int pbv = __shfl(pk2[rt][2 * kt + 1][t & 1], src);
                pb[t] = hi ? pbv : pa;
            }
            u32x4 pbq = { pb[0], pb[1], pb[2], pb[3] };
            u16x8 pbf = __builtin_bit_cast(u16x8, pbq);
            #pragma unroll
            for (int dt = 0; dt < 4; ++dt)
                o_acc[rt][dt] = mfma_bf16(vf[dt], pbf, o_acc[rt][dt]);
        }
    }
    __builtin_amdgcn_s_setprio(0);

    // ---- write partials (bf16 O, f32 m/l); slot = compact triangular idx ----
    const int pidx = bid;
    unsigned short* pob = po + (size_t)pidx * 8192;   // [128][64] bf16
    #pragma unroll
    for (int rt = 0; rt < 2; ++rt) {
        int row = w * 32 + rt * 16 + l15;
        #pragma unroll
        for (int dt = 0; dt < 4; ++dt) {
            unsigned int w0 = cvt_pk_bf16(o_acc[rt][dt][0], o_acc[rt][dt][1]);
            unsigned int w1 = cvt_pk_bf16(o_acc[rt][dt][2], o_acc[rt][dt][3]);
            *(unsigned int*)&pob[row * 64 + dt * 16 + lg * 4]     = w0;
            *(unsigned int*)&pob[row * 64 + dt * 16 + lg * 4 + 2] = w1;
        }
        if (lg == 0) {
            pm[pidx * 128 + row] = msv[rt];
            pl[pidx * 128 + row] = lsv[rt];
        }
    }
}

// --------------------------- phase 2: combine (register-array merge) --------
__global__ __launch_bounds__(256) void attn_combine_kernel(
    const unsigned short* __restrict__ po, const float* __restrict__ pm,
    const float* __restrict__ pl, float* __restrict__ out)
{
    const int blk   = blockIdx.x;          // (b*32 + q128)*4 + slice
    const int slice = blk & 3;
    const int tb    = blk >> 2;            // b*32 + q128
    const int q128  = tb & 31;
    const int b     = tb >> 5;
    const int nch   = q128 + 1;
    const int bslot = b * NTRI + q128 * (q128 + 1) / 2;
    const int row   = slice * 32 + (threadIdx.x >> 3);   // 0..127
    const int d0    = (threadIdx.x & 7) * 8;

    // load all chunk maxima once into registers (static indexing, all in flight)
    float m_i[32];
    #pragma unroll
    for (int i = 0; i < 32; ++i) {
        int ii = (i < nch) ? i : 0;
        m_i[i] = pm[(bslot + ii) * 128 + row];
    }
    float mstar = m_i[0];
    #pragma unroll
    for (int i = 1; i < 32; ++i)
        if (i < nch) mstar = fmaxf(mstar, m_i[i]);

    float lsum = 0.0f;
    float a[8] = {};
    #pragma unroll
    for (int i = 0; i < 32; ++i) {
        if (i < nch) {
            float wi = exp2f(m_i[i] - mstar);
            lsum += wi * pl[(bslot + i) * 128 + row];
            u16x8 v = *(const u16x8*)&po[(size_t)(bslot + i) * 8192 + row * 64 + d0];
            #pragma unroll
            for (int j = 0; j < 8; ++j) {
                unsigned int u = (unsigned int)v[j] << 16;
                a[j] += wi * __builtin_bit_cast(float, u);
            }
        }
    }
    const float inv = 1.0f / lsum;
    float* op = out + (size_t)(b * T_SEQ + q128 * 128 + row) * DH + d0;
    f32x4 o0 = { a[0] * inv, a[1] * inv, a[2] * inv, a[3] * inv };
    f32x4 o1 = { a[4] * inv, a[5] * inv, a[6] * inv, a[7] * inv };
    *(f32x4*)op = o0;
    *(f32x4*)(op + 4) = o1;
}

// --------------------------- fallback: direct (global K/V reads) ------------
__global__ __launch_bounds__(64, 4) void attn_direct_kernel(
    const unsigned short* __restrict__ qg, const unsigned short* __restrict__ kg,
    const unsigned short* __restrict__ vt, float* __restrict__ out)
{
    const int bid = blockIdx.x;           // b*128 + q32
    const int q32 = bid & 127;
    const int b   = bid >> 7;
    const int l = threadIdx.x, l15 = l & 15, lg = l >> 4;
    const int qrow0 = q32 * 32;
    const int base  = b * T_SEQ;
    const unsigned short* kp = kg + (size_t)base * DH;
    const unsigned short* vp = vt + (size_t)b * DH * T_SEQ;

    u16x8 qf[2][2];
    #pragma unroll
    for (int rt = 0; rt < 2; ++rt) {
        const unsigned short* qrow = qg + (base + qrow0 + rt * 16 + l15) * DH;
        qf[rt][0] = *(const u16x8*)(qrow + 0 + lg * 8);
        qf[rt][1] = *(const u16x8*)(qrow + 32 + lg * 8);
    }

    f32x4 o_acc[2][4];
    float m_run[2], l_run[2];
    #pragma unroll
    for (int rt = 0; rt < 2; ++rt) {
        #pragma unroll
        for (int dt = 0; dt < 4; ++dt) o_acc[rt][dt] = f32x4{};
        m_run[rt] = -1e30f; l_run[rt] = 0.0f;
    }

    const int src0 = l15 + 32 * (lg & 1);
    const int src1 = src0 + 16;
    const bool hi  = (lg >> 1) != 0;

    for (int kv0 = 0; kv0 <= qrow0 + 31; kv0 += KVB) {
        u16x8 kf[4][2];
        #pragma unroll
        for (int nt = 0; nt < 4; ++nt)
            #pragma unroll
            for (int kt = 0; kt < 2; ++kt)
                kf[nt][kt] = *(const u16x8*)(kp + (kv0 + nt * 16 + l15) * DH
                                                + kt * 32 + lg * 8);
        f32x4 s[2][4];
        #pragma unroll
        for (int rt = 0; rt < 2; ++rt)
            #pragma unroll
            for (int nt = 0; nt < 4; ++nt) {
                f32x4 a = {};
                a = mfma_bf16(kf[nt][0], qf[rt][0], a);
                a = mfma_bf16(kf[nt][1], qf[rt][1], a);
                s[rt][nt] = a;
            }
        if (kv0 + KVB - 1 > qrow0) {
            #pragma unroll
            for (int rt = 0; rt < 2; ++rt)
                #pragma unroll
                for (int nt = 0; nt < 4; ++nt)
                    #pragma unroll
                    for (int rr = 0; rr < 4; ++rr) {
                        int kj = kv0 + nt * 16 + lg * 4 + rr;
                        int qi = qrow0 + rt * 16 + l15;
                        if (kj > qi) s[rt][nt][rr] = -1e30f;
                    }
        }
        float sc2[2];
        bool grow = false;
        unsigned int pk[2][4][2];
        #pragma unroll
        for (int rt = 0; rt < 2; ++rt) {
            float mx = s[rt][0][0];
            #pragma unroll
            for (int nt = 0; nt < 4; ++nt)
                #pragma unroll
                for (int rr = 0; rr < 4; ++rr)
                    mx = fmaxf(mx, s[rt][nt][rr]);
            mx = fmaxf(mx, __shfl_xor(mx, 16));
            mx = fmaxf(mx, __shfl_xor(mx, 32));
            float mold = m_run[rt];
            float mnew = fmaxf(mold, mx);
            grow |= (mx > mold);
            float sc = exp2f(mold - mnew);
            sc2[rt] = sc;
            m_run[rt] = mnew;
            float rs = 0.0f;
            #pragma unroll
            for (int nt = 0; nt < 4; ++nt)
                #pragma unroll
                for (int rr = 0; rr < 4; ++rr) {
                    float p = exp2f(s[rt][nt][rr] - mnew);
                    s[rt][nt][rr] = p;
                    rs += p;
                }
            rs += __shfl_xor(rs, 16);
            rs += __shfl_xor(rs, 32);
            l_run[rt] = l_run[rt] * sc + rs;
            #pragma unroll
            for (int nt = 0; nt < 4; ++nt) {
                pk[rt][nt][0] = cvt_pk_bf16(s[rt][nt][0], s[rt][nt][1]);
                pk[rt][nt][1] = cvt_pk_bf16(s[rt][nt][2], s[rt][nt][3]);
            }
        }
        if (__any(grow)) {
            #pragma unroll
            for (int rt = 0; rt < 2; ++rt)
                #pragma unroll
                for (int dt = 0; dt < 4; ++dt)
                    o_acc[rt][dt] *= sc2[rt];
        }
        #pragma unroll
        for (int kt = 0; kt < 2; ++kt) {
            u16x8 vf[4];
            #pragma unroll
            for (int dt = 0; dt < 4; ++dt)
                vf[dt] = *(const u16x8*)(vp + (size_t)(dt * 16 + l15) * T_SEQ
                                            + kv0 + kt * 32 + lg * 8);
            #pragma unroll
            for (int rt = 0; rt < 2; ++rt) {
                unsigned int pb[4];
                #pragma unroll
                for (int t = 0; t < 4; ++t) {
                    int src = (t < 2) ? src0 : src1;
                    unsigned int pa  = __shfl(pk[rt][2 * kt][t & 1], src);
                    unsigned int pbv = __shfl(pk[rt][2 * kt + 1][t & 1], src);
                    pb[t] = hi ? pbv : pa;
                }
                u32x4 pbq = { pb[0], pb[1], pb[2], pb[3] };
                u16x8 pbf = __builtin_bit_cast(u16x8, pbq);
                #pragma unroll
                for (int dt = 0; dt < 4; ++dt)
                    o_acc[rt][dt] = mfma_bf16(vf[dt], pbf, o_acc[rt][dt]);
            }
        }
    }

    #pragma unroll
    for (int rt = 0; rt < 2; ++rt) {
        float inv = 1.0f / l_run[rt];
        int row = base + qrow0 + rt * 16 + l15;
        #pragma unroll
        for (int dt = 0; dt < 4; ++dt) {
            f32x4 ov = o_acc[rt][dt] * inv;
            *(f32x4*)&out[(size_t)row * DH + dt * 16 + lg * 4] = ov;
        }
    }
}

// ---------------------------------------------------------------------------
extern "C" void kernel_launch(void* const* d_in, const int* in_sizes, int n_in,
                              void* d_out, int out_size, void* d_ws, size_t ws_size,
                              hipStream_t stream)
{
    const float* x  = (const float*)d_in[0];
    const float* wq = (const float*)d_in[1];
    const float* wk = (const float*)d_in[2];
    const float* wv = (const float*)d_in[3];
    float* out = (float*)d_out;

    // ws layout:
    //   wt  bf16 [3][64][128]        @ 0        (reserve 64 KB)
    //   qw  bf16 [16384][64]         @ 65536    (2 MB)
    //   kw  bf16 [16384][64]         @ +2 MB
    //   vt  bf16 [4][64][4096]       @ +4 MB
    //   po  bf16 [2112][128][64]     @ 6356992  (34.6 MB, compact triangular)
    //   pm/pl f32 [2112][128]        (1.08 MB each)
    unsigned short* wt = (unsigned short*)d_ws;
    unsigned short* qw = (unsigned short*)((char*)d_ws + 65536);
    unsigned short* kw = qw + (size_t)16384 * DH;
    unsigned short* vt = kw + (size_t)16384 * DH;

    const size_t slots  = 4u * NTRI;                  // 2112
    const size_t po_off = 65536u + 3u * 16384u * DH * 2u;
    const size_t po_sz  = slots * 8192 * 2;
    const size_t pm_off = po_off + po_sz;
    const size_t pl_off = pm_off + slots * 128 * 4;
    const size_t need   = pl_off + slots * 128 * 4;

    prep_w_kernel<<<96, 256, 0, stream>>>(wq, wk, wv, wt);
    proj_kernel<<<1024, 64, 0, stream>>>(x, wt, qw, kw, vt);

    if (ws_size >= need) {
        unsigned short* po = (unsigned short*)((char*)d_ws + po_off);
        float* pm = (float*)((char*)d_ws + pm_off);
        float* pl = (float*)((char*)d_ws + pl_off);
        attn_partial_kernel<<<4 * NTRI, 256, 0, stream>>>(qw, kw, vt, po, pm, pl);
        attn_combine_kernel<<<4 * 32 * 4, 256, 0, stream>>>(po, pm, pl, out);
    } else {
        attn_direct_kernel<<<4 * 128, 64, 0, stream>>>(qw, kw, vt, out);
    }
}

// Round 18
// 58.705 us; speedup vs baseline: 1.0234x; 1.0031x over previous
//
#include <hip/hip_runtime.h>
#include <hip/hip_bf16.h>

// ---------------------------------------------------------------------------
// Fused causal attention head: B=4, T=4096, E=128, D=64, fp32 in/out.
// prep_w (W -> WT bf16) -> proj (x@W MFMA; q,k row-major bf16, q pre-scaled
// by 0.125*log2(e); V transposed to vt[d][t]) -> attn_partial (uniform
// triangular grid of 128q x 128k blocks, XCD-chunked swizzle, XOR-swizzled
// 32KB LDS, swapped-QK^T with PLAIN per-chunk softmax (no online rescale:
// S over all 128 keys first, one reduce/exp/pack per rt, shared-V PV pass))
// -> attn_combine (register-array merge). Fallback: direct kernel.
// [R18 = R17 verbatim: session-best configuration, 58.9 us]
// ---------------------------------------------------------------------------

typedef __attribute__((ext_vector_type(4))) float  f32x4;
typedef __attribute__((ext_vector_type(4))) unsigned int u32x4;
typedef __attribute__((ext_vector_type(8))) __bf16 bf16x8;
typedef __attribute__((ext_vector_type(8))) unsigned short u16x8;
typedef __attribute__((ext_vector_type(4))) unsigned short u16x4;

#define T_SEQ 4096
#define DH    64
#define EDIM  128
#define KVB   64
#define QSCALE 0.18033688f   // 0.125 * log2(e): softmax in exp2 domain
#define NTRI  528            // 32*33/2 causal blocks per batch

__device__ __forceinline__ unsigned short f2bf(float f) {
    unsigned int x = __builtin_bit_cast(unsigned int, f);
    unsigned int r = x + 0x7fffu + ((x >> 16) & 1u);   // RNE
    return (unsigned short)(r >> 16);
}

__device__ __forceinline__ unsigned int cvt_pk_bf16(float lo, float hi) {
    unsigned int d;
    asm("v_cvt_pk_bf16_f32 %0, %1, %2" : "=v"(d) : "v"(lo), "v"(hi));
    return d;
}

__device__ __forceinline__ f32x4 mfma_bf16(u16x8 a, u16x8 b, f32x4 c) {
    return __builtin_amdgcn_mfma_f32_16x16x32_bf16(
        __builtin_bit_cast(bf16x8, a), __builtin_bit_cast(bf16x8, b), c, 0, 0, 0);
}

// swizzled LDS byte offsets (write and read use the same involution)
__device__ __forceinline__ int kswz(int row, int bcol) {   // K: [128 rows][128B]
    return row * 128 + (bcol ^ ((row & 7) << 4));
}
__device__ __forceinline__ int vswz(int row, int bcol) {   // V: [64 rows][256B]
    return row * 256 + (bcol ^ ((row & 15) << 4));
}

// --------------------------- prep_w -----------------------------------------
__global__ __launch_bounds__(256) void prep_w_kernel(
    const float* __restrict__ wq, const float* __restrict__ wk,
    const float* __restrict__ wv, unsigned short* __restrict__ wt)
{
    int o = blockIdx.x * 256 + threadIdx.x;
    int m   = o >> 13;
    int rem = o & 8191;
    int d = rem >> 7, e = rem & 127;
    const float* W = (m == 0) ? wq : (m == 1) ? wk : wv;
    wt[o] = f2bf(W[e * DH + d]);
}

// --------------------------- proj: q,k row-major; v transposed --------------
__global__ __launch_bounds__(64) void proj_kernel(
    const float* __restrict__ x, const unsigned short* __restrict__ wt,
    unsigned short* __restrict__ qw, unsigned short* __restrict__ kw,
    unsigned short* __restrict__ vt)
{
    const int l   = threadIdx.x;
    const int l15 = l & 15;
    const int lg  = l >> 4;
    const int row0 = blockIdx.x * 16;      // global row (b*4096 + t)
    const int b    = row0 >> 12;
    const int t0   = row0 & 4095;

    u16x8 af[4];
    #pragma unroll
    for (int kt = 0; kt < 4; ++kt) {
        const float* xp = x + (row0 + l15) * EDIM + kt * 32 + lg * 8;
        f32x4 a = *(const f32x4*)xp;
        f32x4 bb = *(const f32x4*)(xp + 4);
        af[kt] = u16x8{ f2bf(a[0]), f2bf(a[1]), f2bf(a[2]), f2bf(a[3]),
                        f2bf(bb[0]), f2bf(bb[1]), f2bf(bb[2]), f2bf(bb[3]) };
    }

    unsigned short* outs[2] = { qw, kw };
    #pragma unroll
    for (int m = 0; m < 2; ++m) {
        #pragma unroll
        for (int nt = 0; nt < 4; ++nt) {
            f32x4 acc = {};
            #pragma unroll
            for (int kt = 0; kt < 4; ++kt) {
                u16x8 bfrag = *(const u16x8*)(wt + (m * 64 + nt * 16 + l15) * EDIM
                                                 + kt * 32 + lg * 8);
                acc = mfma_bf16(af[kt], bfrag, acc);
            }
            const float sc = (m == 0) ? QSCALE : 1.0f;
            #pragma unroll
            for (int r = 0; r < 4; ++r)
                outs[m][(row0 + lg * 4 + r) * DH + nt * 16 + l15] = f2bf(acc[r] * sc);
        }
    }

    // v: store transposed vt[b][d][t]
    #pragma unroll
    for (int nt = 0; nt < 4; ++nt) {
        f32x4 acc = {};
        #pragma unroll
        for (int kt = 0; kt < 4; ++kt) {
            u16x8 bfrag = *(const u16x8*)(wt + (2 * 64 + nt * 16 + l15) * EDIM
                                             + kt * 32 + lg * 8);
            acc = mfma_bf16(af[kt], bfrag, acc);
        }
        u16x4 pv = { f2bf(acc[0]), f2bf(acc[1]), f2bf(acc[2]), f2bf(acc[3]) };
        *(u16x4*)(vt + ((size_t)(b * DH + nt * 16 + l15)) * T_SEQ + t0 + lg * 4) = pv;
    }
}

// --------------------------- phase 1: uniform triangular flash --------------
__global__ __launch_bounds__(256, 3) void attn_partial_kernel(
    const unsigned short* __restrict__ qg, const unsigned short* __restrict__ kg,
    const unsigned short* __restrict__ vt,
    unsigned short* __restrict__ po, float* __restrict__ pm, float* __restrict__ pl)
{
    // XCD-chunked swizzle: grid 2112 = 8 x 264, bijective since 2112 % 8 == 0.
    const int phys = blockIdx.x;
    const int bid  = (phys & 7) * 264 + (phys >> 3);
    // compact triangular decode: bid -> (b, q128, ch), ch in [0, q128]
    const int b   = bid / NTRI;
    const int i   = bid - b * NTRI;
    int q = (int)((__builtin_sqrtf((float)(8 * i + 1)) - 1.0f) * 0.5f);
    while (q * (q + 1) / 2 > i) --q;
    while ((q + 1) * (q + 2) / 2 <= i) ++q;
    const int q128 = q;
    const int ch   = i - q * (q + 1) / 2;

    __shared__ char K_ldsb[128 * 128];     // 128 keys x 64 d bf16, swizzled
    __shared__ char V_ldsb[64 * 256];      // 64 d x 128 keys bf16, swizzled

    const int tid = threadIdx.x;
    const int w   = tid >> 6;
    const int l   = tid & 63;
    const int l15 = l & 15;
    const int lg  = l >> 4;

    const int base   = b * T_SEQ;
    const int qrow0w = q128 * 128 + w * 32;
    const int kvb    = ch * 128;           // every chunk is 128 keys

    const unsigned short* kgB = kg + (size_t)base * DH;
    const unsigned short* vtB = vt + (size_t)b * DH * T_SEQ;

    // ---- stage K[128][64] and V^T[64][128], coalesced reg->LDS, swizzled ----
    {
        u16x8 kr[4], vr[4];
        #pragma unroll
        for (int j = 0; j < 4; ++j) {
            int gi = tid + j * 256;                // 0..1023
            kr[j] = *(const u16x8*)(kgB + (size_t)(kvb + (gi >> 3)) * DH + (gi & 7) * 8);
            vr[j] = *(const u16x8*)(vtB + (size_t)(gi >> 4) * T_SEQ + kvb + (gi & 15) * 8);
        }
        #pragma unroll
        for (int j = 0; j < 4; ++j) {
            int gi = tid + j * 256;
            *(u16x8*)&K_ldsb[kswz(gi >> 3, (gi & 7) * 16)]  = kr[j];
            *(u16x8*)&V_ldsb[vswz(gi >> 4, (gi & 15) * 16)] = vr[j];
        }
    }

    // Q fragments
    u16x8 qf[2][2];
    #pragma unroll
    for (int rt = 0; rt < 2; ++rt) {
        const unsigned short* qrow = qg + (base + qrow0w + rt * 16 + l15) * DH;
        qf[rt][0] = *(const u16x8*)(qrow + 0 + lg * 8);
        qf[rt][1] = *(const u16x8*)(qrow + 32 + lg * 8);
    }

    f32x4 o_acc[2][4];
    #pragma unroll
    for (int rt = 0; rt < 2; ++rt)
        #pragma unroll
        for (int dt = 0; dt < 4; ++dt) o_acc[rt][dt] = f32x4{};

    const int src0 = l15 + 32 * (lg & 1);
    const int src1 = src0 + 16;
    const bool hi  = (lg >> 1) != 0;

    __syncthreads();

    // tile-1 (keys kvb+64..kvb+127) has any unmasked keys for this wave?
    const bool t1        = (kvb + 64 <= qrow0w + 31);
    const bool need_mask = (kvb + 127 > qrow0w);

    float msv[2], lsv[2];
    unsigned int pk2[2][8][2];

    // ---- per-rt: S over all 128 keys, ONE plain softmax (no online) ----
    #pragma unroll
    for (int rt = 0; rt < 2; ++rt) {
        f32x4 s[8];
        #pragma unroll
        for (int nt = 0; nt < 8; ++nt)
            s[nt] = f32x4{ -1e30f, -1e30f, -1e30f, -1e30f };

        __builtin_amdgcn_s_setprio(1);
        #pragma unroll
        for (int nt = 0; nt < 4; ++nt) {
            int krow = nt * 16 + l15;
            u16x8 k0 = *(const u16x8*)&K_ldsb[kswz(krow, 0 + lg * 16)];
            u16x8 k1 = *(const u16x8*)&K_ldsb[kswz(krow, 64 + lg * 16)];
            f32x4 a = {};
            a = mfma_bf16(k0, qf[rt][0], a);
            a = mfma_bf16(k1, qf[rt][1], a);
            s[nt] = a;
        }
        if (t1) {
            #pragma unroll
            for (int nt = 0; nt < 4; ++nt) {
                int krow = 64 + nt * 16 + l15;
                u16x8 k0 = *(const u16x8*)&K_ldsb[kswz(krow, 0 + lg * 16)];
                u16x8 k1 = *(const u16x8*)&K_ldsb[kswz(krow, 64 + lg * 16)];
                f32x4 a = {};
                a = mfma_bf16(k0, qf[rt][0], a);
                a = mfma_bf16(k1, qf[rt][1], a);
                s[4 + nt] = a;
            }
        }
        __builtin_amdgcn_s_setprio(0);

        if (need_mask) {                       // diagonal chunk only
            const int qi = qrow0w + rt * 16 + l15;
            #pragma unroll
            for (int nt = 0; nt < 8; ++nt)
                #pragma unroll
                for (int rr = 0; rr < 4; ++rr) {
                    int kj = kvb + nt * 16 + lg * 4 + rr;
                    if (kj > qi) s[nt][rr] = -1e30f;
                }
        }

        // plain softmax over the chunk (2 shfls total)
        float mx = s[0][0];
        #pragma unroll
        for (int nt = 0; nt < 8; ++nt)
            #pragma unroll
            for (int rr = 0; rr < 4; ++rr)
                mx = fmaxf(mx, s[nt][rr]);
        mx = fmaxf(mx, __shfl_xor(mx, 16));
        mx = fmaxf(mx, __shfl_xor(mx, 32));

        float rs = 0.0f;
        #pragma unroll
        for (int nt = 0; nt < 8; ++nt) {
            float e0 = exp2f(s[nt][0] - mx);
            float e1 = exp2f(s[nt][1] - mx);
            float e2 = exp2f(s[nt][2] - mx);
            float e3 = exp2f(s[nt][3] - mx);
            rs += (e0 + e1) + (e2 + e3);
            pk2[rt][nt][0] = cvt_pk_bf16(e0, e1);
            pk2[rt][nt][1] = cvt_pk_bf16(e2, e3);
        }
        rs += __shfl_xor(rs, 16);
        rs += __shfl_xor(rs, 32);
        msv[rt] = mx;
        lsv[rt] = rs;
    }

    // ---- PV: 4 k-slices of 32 keys; V-frags shared by both rt ----
    __builtin_amdgcn_s_setprio(1);
    #pragma unroll
    for (int kt = 0; kt < 4; ++kt) {
        if (kt >= 2 && !t1) continue;          // tile-1 fully masked: pk are 0
        u16x8 vf[4];
        #pragma unroll
        for (int dt = 0; dt < 4; ++dt) {
            int vrow = dt * 16 + l15;
            vf[dt] = *(const u16x8*)&V_ldsb[vswz(vrow, kt * 64 + lg * 16)];
        }
        #pragma unroll
        for (int rt = 0; rt < 2; ++rt) {
            unsigned int pb[4];
            #pragma unroll
            for (int t = 0; t < 4; ++t) {
                int src = (t < 2) ? src0 : src1;
                unsigned int pa  = __shfl(pk2[rt][2 * kt][t & 1], src);
                unsigned int pbv = __shfl(pk2[rt][2 * kt + 1][t & 1], src);
                pb[t] = hi ? pbv : pa;
            }
            u32x4 pbq = { pb[0], pb[1], pb[2], pb[3] };
            u16x8 pbf = __builtin_bit_cast(u16x8, pbq);
            #pragma unroll
            for (int dt = 0; dt < 4; ++dt)
                o_acc[rt][dt] = mfma_bf16(vf[dt], pbf, o_acc[rt][dt]);
        }
    }
    __builtin_amdgcn_s_setprio(0);

    // ---- write partials (bf16 O, f32 m/l); slot = compact triangular idx ----
    const int pidx = bid;
    unsigned short* pob = po + (size_t)pidx * 8192;   // [128][64] bf16
    #pragma unroll
    for (int rt = 0; rt < 2; ++rt) {
        int row = w * 32 + rt * 16 + l15;
        #pragma unroll
        for (int dt = 0; dt < 4; ++dt) {
            unsigned int w0 = cvt_pk_bf16(o_acc[rt][dt][0], o_acc[rt][dt][1]);
            unsigned int w1 = cvt_pk_bf16(o_acc[rt][dt][2], o_acc[rt][dt][3]);
            *(unsigned int*)&pob[row * 64 + dt * 16 + lg * 4]     = w0;
            *(unsigned int*)&pob[row * 64 + dt * 16 + lg * 4 + 2] = w1;
        }
        if (lg == 0) {
            pm[pidx * 128 + row] = msv[rt];
            pl[pidx * 128 + row] = lsv[rt];
        }
    }
}

// --------------------------- phase 2: combine (register-array merge) --------
__global__ __launch_bounds__(256) void attn_combine_kernel(
    const unsigned short* __restrict__ po, const float* __restrict__ pm,
    const float* __restrict__ pl, float* __restrict__ out)
{
    const int blk   = blockIdx.x;          // (b*32 + q128)*4 + slice
    const int slice = blk & 3;
    const int tb    = blk >> 2;            // b*32 + q128
    const int q128  = tb & 31;
    const int b     = tb >> 5;
    const int nch   = q128 + 1;
    const int bslot = b * NTRI + q128 * (q128 + 1) / 2;
    const int row   = slice * 32 + (threadIdx.x >> 3);   // 0..127
    const int d0    = (threadIdx.x & 7) * 8;

    // load all chunk maxima once into registers (static indexing, all in flight)
    float m_i[32];
    #pragma unroll
    for (int i = 0; i < 32; ++i) {
        int ii = (i < nch) ? i : 0;
        m_i[i] = pm[(bslot + ii) * 128 + row];
    }
    float mstar = m_i[0];
    #pragma unroll
    for (int i = 1; i < 32; ++i)
        if (i < nch) mstar = fmaxf(mstar, m_i[i]);

    float lsum = 0.0f;
    float a[8] = {};
    #pragma unroll
    for (int i = 0; i < 32; ++i) {
        if (i < nch) {
            float wi = exp2f(m_i[i] - mstar);
            lsum += wi * pl[(bslot + i) * 128 + row];
            u16x8 v = *(const u16x8*)&po[(size_t)(bslot + i) * 8192 + row * 64 + d0];
            #pragma unroll
            for (int j = 0; j < 8; ++j) {
                unsigned int u = (unsigned int)v[j] << 16;
                a[j] += wi * __builtin_bit_cast(float, u);
            }
        }
    }
    const float inv = 1.0f / lsum;
    float* op = out + (size_t)(b * T_SEQ + q128 * 128 + row) * DH + d0;
    f32x4 o0 = { a[0] * inv, a[1] * inv, a[2] * inv, a[3] * inv };
    f32x4 o1 = { a[4] * inv, a[5] * inv, a[6] * inv, a[7] * inv };
    *(f32x4*)op = o0;
    *(f32x4*)(op + 4) = o1;
}

// --------------------------- fallback: direct (global K/V reads) ------------
__global__ __launch_bounds__(64, 4) void attn_direct_kernel(
    const unsigned short* __restrict__ qg, const unsigned short* __restrict__ kg,
    const unsigned short* __restrict__ vt, float* __restrict__ out)
{
    const int bid = blockIdx.x;           // b*128 + q32
    const int q32 = bid & 127;
    const int b   = bid >> 7;
    const int l = threadIdx.x, l15 = l & 15, lg = l >> 4;
    const int qrow0 = q32 * 32;
    const int base  = b * T_SEQ;
    const unsigned short* kp = kg + (size_t)base * DH;
    const unsigned short* vp = vt + (size_t)b * DH * T_SEQ;

    u16x8 qf[2][2];
    #pragma unroll
    for (int rt = 0; rt < 2; ++rt) {
        const unsigned short* qrow = qg + (base + qrow0 + rt * 16 + l15) * DH;
        qf[rt][0] = *(const u16x8*)(qrow + 0 + lg * 8);
        qf[rt][1] = *(const u16x8*)(qrow + 32 + lg * 8);
    }

    f32x4 o_acc[2][4];
    float m_run[2], l_run[2];
    #pragma unroll
    for (int rt = 0; rt < 2; ++rt) {
        #pragma unroll
        for (int dt = 0; dt < 4; ++dt) o_acc[rt][dt] = f32x4{};
        m_run[rt] = -1e30f; l_run[rt] = 0.0f;
    }

    const int src0 = l15 + 32 * (lg & 1);
    const int src1 = src0 + 16;
    const bool hi  = (lg >> 1) != 0;

    for (int kv0 = 0; kv0 <= qrow0 + 31; kv0 += KVB) {
        u16x8 kf[4][2];
        #pragma unroll
        for (int nt = 0; nt < 4; ++nt)
            #pragma unroll
            for (int kt = 0; kt < 2; ++kt)
                kf[nt][kt] = *(const u16x8*)(kp + (kv0 + nt * 16 + l15) * DH
                                                + kt * 32 + lg * 8);
        f32x4 s[2][4];
        #pragma unroll
        for (int rt = 0; rt < 2; ++rt)
            #pragma unroll
            for (int nt = 0; nt < 4; ++nt) {
                f32x4 a = {};
                a = mfma_bf16(kf[nt][0], qf[rt][0], a);
                a = mfma_bf16(kf[nt][1], qf[rt][1], a);
                s[rt][nt] = a;
            }
        if (kv0 + KVB - 1 > qrow0) {
            #pragma unroll
            for (int rt = 0; rt < 2; ++rt)
                #pragma unroll
                for (int nt = 0; nt < 4; ++nt)
                    #pragma unroll
                    for (int rr = 0; rr < 4; ++rr) {
                        int kj = kv0 + nt * 16 + lg * 4 + rr;
                        int qi = qrow0 + rt * 16 + l15;
                        if (kj > qi) s[rt][nt][rr] = -1e30f;
                    }
        }
        float sc2[2];
        bool grow = false;
        unsigned int pk[2][4][2];
        #pragma unroll
        for (int rt = 0; rt < 2; ++rt) {
            float mx = s[rt][0][0];
            #pragma unroll
            for (int nt = 0; nt < 4; ++nt)
                #pragma unroll
                for (int rr = 0; rr < 4; ++rr)
                    mx = fmaxf(mx, s[rt][nt][rr]);
            mx = fmaxf(mx, __shfl_xor(mx, 16));
            mx = fmaxf(mx, __shfl_xor(mx, 32));
            float mold = m_run[rt];
            float mnew = fmaxf(mold, mx);
            grow |= (mx > mold);
            float sc = exp2f(mold - mnew);
            sc2[rt] = sc;
            m_run[rt] = mnew;
            float rs = 0.0f;
            #pragma unroll
            for (int nt = 0; nt < 4; ++nt)
                #pragma unroll
                for (int rr = 0; rr < 4; ++rr) {
                    float p = exp2f(s[rt][nt][rr] - mnew);
                    s[rt][nt][rr] = p;
                    rs += p;
                }
            rs += __shfl_xor(rs, 16);
            rs += __shfl_xor(rs, 32);
            l_run[rt] = l_run[rt] * sc + rs;
            #pragma unroll
            for (int nt = 0; nt < 4; ++nt) {
                pk[rt][nt][0] = cvt_pk_bf16(s[rt][nt][0], s[rt][nt][1]);
                pk[rt][nt][1] = cvt_pk_bf16(s[rt][nt][2], s[rt][nt][3]);
            }
        }
        if (__any(grow)) {
            #pragma unroll
            for (int rt = 0; rt < 2; ++rt)
                #pragma unroll
                for (int dt = 0; dt < 4; ++dt)
                    o_acc[rt][dt] *= sc2[rt];
        }
        #pragma unroll
        for (int kt = 0; kt < 2; ++kt) {
            u16x8 vf[4];
            #pragma unroll
            for (int dt = 0; dt < 4; ++dt)
                vf[dt] = *(const u16x8*)(vp + (size_t)(dt * 16 + l15) * T_SEQ
                                            + kv0 + kt * 32 + lg * 8);
            #pragma unroll
            for (int rt = 0; rt < 2; ++rt) {
                unsigned int pb[4];
                #pragma unroll
                for (int t = 0; t < 4; ++t) {
                    int src = (t < 2) ? src0 : src1;
                    unsigned int pa  = __shfl(pk[rt][2 * kt][t & 1], src);
                    unsigned int pbv = __shfl(pk[rt][2 * kt + 1][t & 1], src);
                    pb[t] = hi ? pbv : pa;
                }
                u32x4 pbq = { pb[0], pb[1], pb[2], pb[3] };
                u16x8 pbf = __builtin_bit_cast(u16x8, pbq);
                #pragma unroll
                for (int dt = 0; dt < 4; ++dt)
                    o_acc[rt][dt] = mfma_bf16(vf[dt], pbf, o_acc[rt][dt]);
            }
        }
    }

    #pragma unroll
    for (int rt = 0; rt < 2; ++rt) {
        float inv = 1.0f / l_run[rt];
        int row = base + qrow0 + rt * 16 + l15;
        #pragma unroll
        for (int dt = 0; dt < 4; ++dt) {
            f32x4 ov = o_acc[rt][dt] * inv;
            *(f32x4*)&out[(size_t)row * DH + dt * 16 + lg * 4] = ov;
        }
    }
}

// ---------------------------------------------------------------------------
extern "C" void kernel_launch(void* const* d_in, const int* in_sizes, int n_in,
                              void* d_out, int out_size, void* d_ws, size_t ws_size,
                              hipStream_t stream)
{
    const float* x  = (const float*)d_in[0];
    const float* wq = (const float*)d_in[1];
    const float* wk = (const float*)d_in[2];
    const float* wv = (const float*)d_in[3];
    float* out = (float*)d_out;

    // ws layout:
    //   wt  bf16 [3][64][128]        @ 0        (reserve 64 KB)
    //   qw  bf16 [16384][64]         @ 65536    (2 MB)
    //   kw  bf16 [16384][64]         @ +2 MB
    //   vt  bf16 [4][64][4096]       @ +4 MB
    //   po  bf16 [2112][128][64]     @ 6356992  (34.6 MB, compact triangular)
    //   pm/pl f32 [2112][128]        (1.08 MB each)
    unsigned short* wt = (unsigned short*)d_ws;
    unsigned short* qw = (unsigned short*)((char*)d_ws + 65536);
    unsigned short* kw = qw + (size_t)16384 * DH;
    unsigned short* vt = kw + (size_t)16384 * DH;

    const size_t slots  = 4u * NTRI;                  // 2112
    const size_t po_off = 65536u + 3u * 16384u * DH * 2u;
    const size_t po_sz  = slots * 8192 * 2;
    const size_t pm_off = po_off + po_sz;
    const size_t pl_off = pm_off + slots * 128 * 4;
    const size_t need   = pl_off + slots * 128 * 4;

    prep_w_kernel<<<96, 256, 0, stream>>>(wq, wk, wv, wt);
    proj_kernel<<<1024, 64, 0, stream>>>(x, wt, qw, kw, vt);

    if (ws_size >= need) {
        unsigned short* po = (unsigned short*)((char*)d_ws + po_off);
        float* pm = (float*)((char*)d_ws + pm_off);
        float* pl = (float*)((char*)d_ws + pl_off);
        attn_partial_kernel<<<4 * NTRI, 256, 0, stream>>>(qw, kw, vt, po, pm, pl);
        attn_combine_kernel<<<4 * 32 * 4, 256, 0, stream>>>(po, pm, pl, out);
    } else {
        attn_direct_kernel<<<4 * 128, 64, 0, stream>>>(qw, kw, vt, out);
    }
}